// Round 12
// baseline (604.177 us; speedup 1.0000x reference)
//
#include <hip/hip_runtime.h>

// V=5000, C=128, K=64. ONE kernel, 16 blocks end-to-end.
// Model from R1-R11 measurements: 16-block fetch-add barrier ~1us; 96-block tree
// barrier ~55us; launch gap ~40-50us. So: one kernel, narrow grid, many cheap barriers.
// Math (R5..R11-proven): E = Ahat Ahat^T + LMB diag(r1r^2+r1i^2), Ahat = Mx^T A,
// H = My^T My; chol(E)/chol(H) congruence -> At(Y) = Y + sum_t L_t Y R_t;
// pipelined Jacobi-PCG (Ghysels-Vanroose, 1 barrier/iter), MAXIT=75 (absmax
// plateaus at 2^-10 by iter<=100; threshold margin 9x).
#define NV 5000
#define LMB 100.0f
#define MAXIT 75
#define TOL 1e-10f
#define NCG 16

// ---- workspace float offsets ----
#define SV_O     0
#define CTRLP_O  256       // flag-tree ints (poison-tolerant): flag[blk*32], go at [4000]
#define CTRL2_O  4352      // cg: cnt int @0; RZ floats @+64 (160); PQ @+264 (160)
#define PART_O   4864      // 80 * 8192
#define AH_O     660224
#define B0_O     668416
#define H_O      676608
#define E_O      680704
#define Z2_O     684800
#define RH_O     688896
#define TB_O     692992
#define LIH_O    697088
#define LIE_O    701184
#define BT_O     705280
#define RSTK_O   709376    // R_t, t=0..2
#define LCT_O    721664    // L_t, t=0..2 (exactly symmetric)
#define WG_O     733952
#define XG_O     738048
#define WS_NEED  742144

__device__ __forceinline__ float aload(const float* p) {
  return __hip_atomic_load(p, __ATOMIC_RELAXED, __HIP_MEMORY_SCOPE_AGENT);
}
__device__ __forceinline__ void astore(float* p, float v) {
  __hip_atomic_store(p, v, __ATOMIC_RELAXED, __HIP_MEMORY_SCOPE_AGENT);
}

// tree-flag barrier (garbage-tolerant; used ONCE at poisoned startup)
__device__ __forceinline__ void gbarT(int* ctrl, int blk, int bt, int nb) {
  __syncthreads();
  int tid = threadIdx.x;
  if (blk == 0) {
    if (tid >= 1 && tid < nb) {
      while (__hip_atomic_load(&ctrl[tid * 32], __ATOMIC_ACQUIRE, __HIP_MEMORY_SCOPE_AGENT) < bt)
        __builtin_amdgcn_s_sleep(1);
    }
    __syncthreads();
    if (tid == 0)
      __hip_atomic_store(&ctrl[4000], bt, __ATOMIC_RELEASE, __HIP_MEMORY_SCOPE_AGENT);
  } else {
    if (tid == 0) {
      __hip_atomic_store(&ctrl[blk * 32], bt, __ATOMIC_RELEASE, __HIP_MEMORY_SCOPE_AGENT);
      while (__hip_atomic_load(&ctrl[4000], __ATOMIC_ACQUIRE, __HIP_MEMORY_SCOPE_AGENT) < bt)
        __builtin_amdgcn_s_sleep(1);
    }
    __syncthreads();
  }
}

// fetch-add barrier (16 blocks, ~1us measured)
__device__ __forceinline__ void gbar(int* cnt, int target) {
  __syncthreads();
  if (threadIdx.x == 0) {
    __hip_atomic_fetch_add(cnt, 1, __ATOMIC_ACQ_REL, __HIP_MEMORY_SCOPE_AGENT);
    while (__hip_atomic_load(cnt, __ATOMIC_ACQUIRE, __HIP_MEMORY_SCOPE_AGENT) < target) {
      __builtin_amdgcn_s_sleep(2);
    }
  }
  __syncthreads();
}

// fused dual reduction -> one atomicAdd each from tid 0
__device__ __forceinline__ void red2a(float v1, float v2, float* red, float* d1, float* d2) {
  int tid = threadIdx.x;
  red[tid] = v1;
  red[256 + tid] = v2;
  __syncthreads();
  if (tid < 128) {
    red[tid] += red[tid + 128];
    red[256 + tid] += red[384 + tid];
  }
  __syncthreads();
  if (tid < 64) {
    float s1 = red[tid] + red[tid + 64];
    float s2 = red[256 + tid] + red[320 + tid];
#pragma unroll
    for (int o = 32; o > 0; o >>= 1) {
      s1 += __shfl_down(s1, o, 64);
      s2 += __shfl_down(s2, o, 64);
    }
    if (tid == 0) { atomicAdd(d1, s1); atomicAdd(d2, s2); }
  }
  __syncthreads();
}

// ---- plain-memory LDS staging + 64x64 GEMM helpers ----
__device__ __forceinline__ void stageN(float* dst, const float* src) {
  for (int e = threadIdx.x; e < 4096; e += 256)
    dst[(e >> 6) * 65 + (e & 63)] = src[e];
}
__device__ __forceinline__ void stageT(float* dst, const float* src) {
  for (int e = threadIdx.x; e < 4096; e += 256)
    dst[(e & 63) * 65 + (e >> 6)] = src[e];
}
__device__ __forceinline__ void mm65(const float* Ls, const float* Rs, float* D) {
  for (int e = threadIdx.x; e < 4096; e += 256) {
    int i = e >> 6, j = e & 63;
    float a0 = 0.f, a1 = 0.f;
#pragma unroll 8
    for (int t = 0; t < 64; t += 2) {
      a0 = fmaf(Ls[i * 65 + t], Rs[t * 65 + j], a0);
      a1 = fmaf(Ls[i * 65 + t + 1], Rs[(t + 1) * 65 + j], a1);
    }
    D[e] = a0 + a1;
  }
}
__device__ __forceinline__ void mm65L(const float* Ls, const float* Rs, float* Ds) {
  for (int e = threadIdx.x; e < 4096; e += 256) {
    int i = e >> 6, j = e & 63;
    float a0 = 0.f, a1 = 0.f;
#pragma unroll 8
    for (int t = 0; t < 64; t += 2) {
      a0 = fmaf(Ls[i * 65 + t], Rs[t * 65 + j], a0);
      a1 = fmaf(Ls[i * 65 + t + 1], Rs[(t + 1) * 65 + j], a1);
    }
    Ds[i * 65 + j] = a0 + a1;
  }
}

// ---- 64x64 SPD Cholesky + explicit L^-1 ----
__device__ void chol_inv(const float* S, float* Li, float* sm) {
  float (*M)[65] = (float (*)[65])sm;
  float (*T)[65] = (float (*)[65])(sm + 64 * 65);
  int tid = threadIdx.x;
  for (int e = tid; e < 4096; e += 256) {
    M[e >> 6][e & 63] = S[e];
    T[e >> 6][e & 63] = 0.f;
  }
  __syncthreads();
  for (int j = 0; j < 64; ++j) {
    float pv = M[j][j];
    __syncthreads();
    float sc = rsqrtf(pv);
    if (tid < 64 - j) M[j + tid][j] *= sc;
    __syncthreads();
    int m = 63 - j, c2 = (m * (m + 1)) >> 1;
    for (int e = tid; e < c2; e += 256) {
      int rp = (int)((sqrtf(8.f * (float)e + 1.f) - 1.f) * 0.5f);
      while (((rp + 1) * (rp + 2)) >> 1 <= e) ++rp;
      while ((rp * (rp + 1)) >> 1 > e) --rp;
      int cp = e - ((rp * (rp + 1)) >> 1);
      int r = j + 1 + rp, c = j + 1 + cp;
      M[r][c] = fmaf(-M[r][j], M[c][j], M[r][c]);
    }
    __syncthreads();
  }
  if (tid < 64) {
    int c = tid;
    T[c][c] = 1.f / M[c][c];
    for (int r = c + 1; r < 64; ++r) {
      float s = 0.f;
      for (int t = c; t < r; ++t) s = fmaf(M[r][t], T[t][c], s);
      T[r][c] = -s / M[r][r];
    }
  }
  __syncthreads();
  for (int e = tid; e < 4096; e += 256) Li[e] = T[e >> 6][e & 63];
}

// ---- apply: At(Y) = Y + sum_{t=0..2} L_t (Y R_t); Y in pT[col][row] ----
__device__ __forceinline__ float at_apply3(const float (*pT)[68], const float* Rown,
                                           float* Tt, const float* LCT,
                                           int lane, int wv, int jown) {
  if (wv >= 1) {
    const float* R0 = Rown + (wv - 1) * 256;
    float a0 = 0.f, a1 = 0.f, a2 = 0.f, a3 = 0.f;
    for (int m = 0; m < 64; ++m) {
      float pv = pT[m][lane];
      a0 = fmaf(pv, R0[m], a0);
      a1 = fmaf(pv, R0[64 + m], a1);
      a2 = fmaf(pv, R0[128 + m], a2);
      a3 = fmaf(pv, R0[192 + m], a3);
    }
    Tt[0 * 192 + (wv - 1) * 64 + lane] = a0;
    Tt[1 * 192 + (wv - 1) * 64 + lane] = a1;
    Tt[2 * 192 + (wv - 1) * 64 + lane] = a2;
    Tt[3 * 192 + (wv - 1) * 64 + lane] = a3;
  }
  __syncthreads();
  const float* Lc = LCT + lane;
  const float* Tw = Tt + wv * 192;
  float b0 = 0.f, b1 = 0.f, b2 = 0.f, b3 = 0.f;
  for (int tk = 0; tk < 192; tk += 4) {
    b0 = fmaf(Lc[(tk + 0) * 64], Tw[tk + 0], b0);
    b1 = fmaf(Lc[(tk + 1) * 64], Tw[tk + 1], b1);
    b2 = fmaf(Lc[(tk + 2) * 64], Tw[tk + 2], b2);
    b3 = fmaf(Lc[(tk + 3) * 64], Tw[tk + 3], b3);
  }
  return pT[jown][lane] + (b0 + b1) + (b2 + b3);
}

__global__ __launch_bounds__(256) void mega_kernel(
    const float* fx, const float* fy, const float* ex, const float* ey,
    const float* Px, const float* Py, const float* Mx, const float* My,
    float* W, float* out) {
  __shared__ float sm[12800];
  __shared__ float red[512];
  __shared__ float scal[3];
  __shared__ float sLd[192], sRd[192];
  int tid = threadIdx.x, blk = blockIdx.x;
  int lane = tid & 63, wv = tid >> 6;
  int* ctrlP = (int*)(W + CTRLP_O);
  int* cnt = (int*)(W + CTRL2_O);
  float* RZ = W + CTRL2_O + 64;
  float* PQ = W + CTRL2_O + 264;

  // ================= P0: proj (5 jobs/block) + sv + H + ctrl-zero ============
  for (int s = 0; s < 5; ++s) {
    int job = blk + 16 * s;           // 0..79
    int mat = (job >= 40), seg = mat ? job - 40 : job;
    const float* P = (mat ? Py : Px);
    const float* f = (mat ? fy : fx);
    int v0 = seg * 125;
    __syncthreads();
    for (int e = tid; e < 8000; e += 256) {
      int rr = e / 125, vv = e - rr * 125;
      sm[rr * 126 + vv] = P[rr * NV + v0 + vv];
    }
    __syncthreads();
    int rg = (tid >> 5) << 3;
    int cq = (tid & 31) << 2;
    float acc[8][4];
#pragma unroll
    for (int u = 0; u < 8; ++u)
#pragma unroll
      for (int v = 0; v < 4; ++v) acc[u][v] = 0.f;
    for (int v5 = 0; v5 < 125; v5 += 5) {
      float4 fv[5];
#pragma unroll
      for (int q = 0; q < 5; ++q)
        fv[q] = *(const float4*)(f + (size_t)(v0 + v5 + q) * 128 + cq);
#pragma unroll
      for (int q = 0; q < 5; ++q) {
#pragma unroll
        for (int u = 0; u < 8; ++u) {
          float pv = sm[(rg + u) * 126 + v5 + q];
          acc[u][0] = fmaf(pv, fv[q].x, acc[u][0]);
          acc[u][1] = fmaf(pv, fv[q].y, acc[u][1]);
          acc[u][2] = fmaf(pv, fv[q].z, acc[u][2]);
          acc[u][3] = fmaf(pv, fv[q].w, acc[u][3]);
        }
      }
    }
    float* O = W + PART_O + (size_t)job * 8192;
#pragma unroll
    for (int u = 0; u < 8; ++u)
      *(float4*)(O + (rg + u) * 128 + cq) = make_float4(acc[u][0], acc[u][1], acc[u][2], acc[u][3]);
  }
  __syncthreads();
  if (blk == 0) {
    for (int e = tid; e < 512; e += 256) ((int*)(W + CTRL2_O))[e] = 0;
  } else if (blk == 1) {
    if (tid < 64) {
      float vx = ex[tid], vy = ey[tid];
      float m = fmaxf(vx, vy);
#pragma unroll
      for (int o = 32; o > 0; o >>= 1) m = fmaxf(m, __shfl_xor(m, o, 64));
      float g1 = sqrtf(vx / m), g2 = sqrtf(vy / m);   // GAMMA = 0.5
      float d1 = 1.f / fmaf(g1, g1, 1.f), d2 = 1.f / fmaf(g2, g2, 1.f);
      W[SV_O + tid] = g1 * d1;          // r1r
      W[SV_O + 64 + tid] = d1;          // r1i
      W[SV_O + 128 + tid] = g2 * d2;    // d2r
      W[SV_O + 192 + tid] = d2;         // d2i
    }
  } else if (blk == 2 || blk == 3) {
    for (int e = tid; e < 4096; e += 256) sm[(e >> 6) * 65 + (e & 63)] = My[e];
    __syncthreads();
    int base = (blk - 2) * 2048;
    for (int e = tid; e < 2048; e += 256) {
      int i = (base + e) >> 6, j = (base + e) & 63;
      float a0 = 0.f, a1 = 0.f;
#pragma unroll 8
      for (int t = 0; t < 64; t += 2) {
        a0 = fmaf(sm[t * 65 + i], sm[t * 65 + j], a0);
        a1 = fmaf(sm[(t + 1) * 65 + i], sm[(t + 1) * 65 + j], a1);
      }
      W[H_O + base + e] = a0 + a1;
    }
  }
  gbarT(ctrlP, blk, 1, NCG);     // poison-tolerant; also publishes ctrl-zero
  int bt = 0;

  // ================= P1: Ahat (0-7) + cholH (8) + B0 (9-15) ==================
  if (blk < 8) {
    int c0 = blk * 16;
    float* ssum = sm;          // [64][17]
    float* mxs = sm + 1088;    // [64][65]
    for (int e = tid; e < 4096; e += 256) mxs[(e >> 6) * 65 + (e & 63)] = Mx[e];
    for (int e = tid; e < 1024; e += 256) {
      int t = e >> 4, cl = e & 15;
      float s = 0.f;
#pragma unroll 8
      for (int p = 0; p < 40; ++p) s += W[PART_O + (size_t)p * 8192 + t * 128 + c0 + cl];
      ssum[t * 17 + cl] = s;
    }
    __syncthreads();
    for (int e = tid; e < 1024; e += 256) {
      int i = e >> 4, cl = e & 15;
      float a0 = 0.f, a1 = 0.f;
#pragma unroll 8
      for (int t = 0; t < 64; t += 2) {
        a0 = fmaf(mxs[t * 65 + i], ssum[t * 17 + cl], a0);
        a1 = fmaf(mxs[(t + 1) * 65 + i], ssum[(t + 1) * 17 + cl], a1);
      }
      W[AH_O + i * 128 + c0 + cl] = a0 + a1;
    }
  } else if (blk == 8) {
    chol_inv(W + H_O, W + LIH_O, sm);
  } else {
    int st = (blk - 9) * 1184, en = st + 1184;
    if (en > 8192) en = 8192;
    for (int e = st + tid; e < en; e += 256) {
      float s = 0.f;
#pragma unroll 8
      for (int p = 0; p < 40; ++p) s += W[PART_O + (size_t)(40 + p) * 8192 + e];
      W[B0_O + e] = s;
    }
  }
  gbar(cnt, (++bt) * NCG);

  // ============ P2: E (0-3) + Z2 (4-7) + t-chains (8-10) ============
  if (blk < 4) {
    for (int e = tid; e < 8192; e += 256) {
      int i = e >> 7, c = e & 127;
      sm[c * 65 + i] = W[AH_O + e];
    }
    __syncthreads();
    int i0 = blk * 16;
    for (int e = tid; e < 1024; e += 256) {
      int i = i0 + (e >> 6), j = e & 63;
      float a0 = 0.f, a1 = 0.f;
#pragma unroll 8
      for (int c = 0; c < 128; c += 2) {
        a0 = fmaf(sm[c * 65 + i], sm[c * 65 + j], a0);
        a1 = fmaf(sm[(c + 1) * 65 + i], sm[(c + 1) * 65 + j], a1);
      }
      float acc = a0 + a1;
      if (i == j) {
        float a = W[SV_O + i], b = W[SV_O + 64 + i];
        acc += LMB * (a * a + b * b);
      }
      W[E_O + i * 64 + j] = acc;
    }
  } else if (blk < 8) {
    int i0 = (blk - 4) * 16;
    for (int e = tid; e < 8192; e += 256) {
      int j = e >> 7, c = e & 127;
      sm[c * 65 + j] = W[B0_O + e];
    }
    for (int e = tid; e < 2048; e += 256) {
      int il = e >> 7, c = e & 127;
      sm[8320 + c * 17 + il] = W[AH_O + (i0 + il) * 128 + c];
    }
    __syncthreads();
    for (int e = tid; e < 1024; e += 256) {
      int il = e >> 6, j = e & 63;
      float a0 = 0.f, a1 = 0.f;
#pragma unroll 8
      for (int c = 0; c < 128; c += 2) {
        a0 = fmaf(sm[8320 + c * 17 + il], sm[c * 65 + j], a0);
        a1 = fmaf(sm[8320 + (c + 1) * 17 + il], sm[(c + 1) * 65 + j], a1);
      }
      W[Z2_O + (i0 + il) * 64 + j] = a0 + a1;
    }
  } else if (blk >= 8 && blk <= 10) {
    int t = blk - 8;
    float* smA = sm;            // LiH
    float* smB = sm + 4160;     // Q_t / QT_t
    float* smC = sm + 8320;     // U_t
    float* sv = sm + 12480;
    for (int e = tid; e < 4096; e += 256) smA[(e >> 6) * 65 + (e & 63)] = W[LIH_O + e];
    if (tid < 256) sv[tid] = W[SV_O + tid];
    __syncthreads();
    for (int e = tid; e < 4096; e += 256) {
      int k = e >> 6, b = e & 63;
      float h = W[H_O + e], v;
      if (t == 0) v = h * (sv[128 + k] * sv[128 + b] + sv[192 + k] * sv[192 + b]);
      else if (t == 1) v = h * (sv[128 + k] + sv[128 + b]);
      else v = h * (sv[192 + k] + sv[192 + b]);
      smB[k * 65 + b] = v;
    }
    __syncthreads();
    mm65L(smA, smB, smC);
    __syncthreads();
    for (int e = tid; e < 4096; e += 256) {
      int i = e >> 6, j = e & 63;
      float a0 = 0.f, a1 = 0.f;
#pragma unroll 8
      for (int b = 0; b < 64; b += 2) {
        a0 = fmaf(smC[i * 65 + b], smA[j * 65 + b], a0);
        a1 = fmaf(smC[i * 65 + b + 1], smA[j * 65 + b + 1], a1);
      }
      smB[i * 65 + j] = a0 + a1;
    }
    __syncthreads();
    for (int e = tid; e < 4096; e += 256) {
      int a = e >> 6, b = e & 63;
      W[RSTK_O + t * 4096 + e] = 0.5f * (smB[a * 65 + b] + smB[b * 65 + a]);
    }
  }
  gbar(cnt, (++bt) * NCG);

  // ============ P3: cholE -> LCT chain (0) + RH = Z2 H (1) ============
  if (blk == 0) {
    chol_inv(W + E_O, W + LIE_O, sm);
    __syncthreads();
    for (int e = tid; e < 4096; e += 256) sm[(e >> 6) * 65 + (e & 63)] = W[LIE_O + e];
    if (tid < 128) sm[4160 + tid] = W[SV_O + tid];
    __syncthreads();
    for (int e = tid; e < 4096; e += 256) {
      int i = e >> 6, j = e & 63;
      float a0 = 0.f, ar = 0.f, ai = 0.f;
#pragma unroll 4
      for (int k = 0; k < 64; ++k) {
        float l = sm[i * 65 + k] * sm[j * 65 + k];
        a0 += l;
        ar = fmaf(l, sm[4160 + k], ar);
        ai = fmaf(l, sm[4224 + k], ai);
      }
      W[LCT_O + e] = LMB * a0;
      W[LCT_O + 4096 + e] = -LMB * ar;
      W[LCT_O + 8192 + e] = -LMB * ai;
    }
  } else if (blk == 1) {
    stageN(sm, W + Z2_O); stageN(sm + 4160, W + H_O);
    __syncthreads();
    mm65(sm, sm + 4160, W + RH_O);
  }
  gbar(cnt, (++bt) * NCG);

  // ============ P4: TB = LiE RH -> BT = TB LiH^T (block 0 chained) ============
  if (blk == 0) {
    stageN(sm, W + LIE_O); stageN(sm + 4160, W + RH_O);
    __syncthreads();
    mm65(sm, sm + 4160, W + TB_O);
    __syncthreads();
    stageN(sm, W + TB_O); stageT(sm + 4160, W + LIH_O);
    __syncthreads();
    mm65(sm, sm + 4160, W + BT_O);
  }
  gbar(cnt, (++bt) * NCG);

  // ================= CG: pipelined Jacobi-PCG (R8 verbatim) ==================
  {
    float (*pT)[68] = (float (*)[68])sm;
    float* Rown = sm + 4352;
    float* Tt = sm + 5120;
    const float* BT = W + BT_O;
    const float* RSTK = W + RSTK_O;
    const float* LCT = W + LCT_O;
    float* wg = W + WG_O;
    int j0 = blk * 4, jown = j0 + wv;

    for (int e = tid; e < 768; e += 256) {
      int t = e >> 8, jl = (e >> 6) & 3, m = e & 63;
      Rown[t * 256 + jl * 64 + m] = RSTK[(t * 64 + j0 + jl) * 64 + m];
    }
    if (tid < 192) {
      int t = tid >> 6, i = tid & 63;
      sLd[tid] = LCT[t * 4096 + i * 64 + i];
      sRd[tid] = RSTK[t * 4096 + i * 64 + i];
    }
    __syncthreads();
    float invd = 1.f / (1.f + sLd[lane] * sRd[jown] + sLd[64 + lane] * sRd[64 + jown] +
                        sLd[128 + lane] * sRd[128 + jown]);
    for (int u = 0; u < 16; ++u) {
      int g = u * 256 + tid;               // g = col*64+row
      int col = g >> 6, row = g & 63;
      float den = 1.f + sLd[row] * sRd[col] + sLd[64 + row] * sRd[64 + col] +
                  sLd[128 + row] * sRd[128 + col];
      pT[col][row] = BT[row * 64 + col] / den;
    }
    __syncthreads();
    float u_l = pT[jown][lane];
    float w_l = at_apply3(pT, Rown, Tt, LCT, lane, wv, jown);
    float r_l = BT[lane * 64 + jown];
    float m_l = invd * w_l;
    astore(&wg[jown * 64 + lane], m_l);
    red2a(r_l * u_l, w_l * u_l, red, &RZ[0], &PQ[0]);
    gbar(cnt, (++bt) * NCG);

    float p_l = 0.f, q_l = 0.f, z_l = 0.f, s_l = 0.f, x_l = 0.f;
    float gprev = 1.f, aprev = 1.f, g0 = 1.f;
    for (int j = 0; j < MAXIT; ++j) {
      if (tid == 0) {
        scal[0] = aload(&RZ[j]);
        scal[1] = aload(&PQ[j]);
        scal[2] = aload(&RZ[0]);
      }
      __syncthreads();
      float gj = scal[0], dj = scal[1];
      if (j == 0) g0 = scal[2];
      if (j > 0 && fabsf(gj) < TOL * fabsf(g0)) break;
      float bj = (j == 0) ? 0.f : gj / gprev;
      float aj = (j == 0) ? gj / dj : gj / (dj - bj * gj / aprev);
      for (int u = 0; u < 16; ++u) {
        int g = u * 256 + tid;
        pT[g >> 6][g & 63] = aload(&wg[g]);
      }
      __syncthreads();
      float n_l = at_apply3(pT, Rown, Tt, LCT, lane, wv, jown);
      z_l = fmaf(bj, z_l, n_l);
      q_l = fmaf(bj, q_l, m_l);
      s_l = fmaf(bj, s_l, w_l);
      p_l = fmaf(bj, p_l, u_l);
      x_l = fmaf(aj, p_l, x_l);
      r_l = fmaf(-aj, s_l, r_l);
      u_l = fmaf(-aj, q_l, u_l);
      w_l = fmaf(-aj, z_l, w_l);
      m_l = invd * w_l;
      astore(&wg[jown * 64 + lane], m_l);
      red2a(r_l * u_l, w_l * u_l, red, &RZ[j + 1], &PQ[j + 1]);
      gprev = gj; aprev = aj;
      gbar(cnt, (++bt) * NCG);
    }
    astore(&W[XG_O + jown * 64 + lane], x_l);   // Y col-major
    gbar(cnt, (++bt) * NCG);
  }

  // ================= finish (block 0): out = (Mx LiE^T Y LiH)^T ==============
  if (blk == 0) {
    float* Ys = sm;           // [64][65]
    float* Ms2 = sm + 4160;   // [64][65]
    for (int e = tid; e < 4096; e += 256) Ys[(e >> 6) * 65 + (e & 63)] = aload(W + XG_O + e);
    for (int e = tid; e < 4096; e += 256) Ms2[(e >> 6) * 65 + (e & 63)] = W[LIE_O + e];
    __syncthreads();
    for (int e = tid; e < 4096; e += 256) {   // V1 = LiE^T Y  (Ys[j][i] = Y[i][j])
      int t = e >> 6, b = e & 63;
      float acc = 0.f;
#pragma unroll 8
      for (int a = 0; a < 64; ++a) acc = fmaf(Ms2[a * 65 + t], Ys[b * 65 + a], acc);
      W[WG_O + t * 64 + b] = acc;
    }
    __syncthreads();
    for (int e = tid; e < 4096; e += 256) Ys[(e >> 6) * 65 + (e & 63)] = W[WG_O + e];
    for (int e = tid; e < 4096; e += 256) Ms2[(e >> 6) * 65 + (e & 63)] = W[LIH_O + e];
    __syncthreads();
    for (int e = tid; e < 4096; e += 256) {   // WH = V1 LiH
      int t = e >> 6, c = e & 63;
      float acc = 0.f;
#pragma unroll 8
      for (int b = 0; b < 64; ++b) acc = fmaf(Ys[t * 65 + b], Ms2[b * 65 + c], acc);
      W[WG_O + t * 64 + c] = acc;
    }
    __syncthreads();
    for (int e = tid; e < 4096; e += 256) Ys[(e >> 6) * 65 + (e & 63)] = W[WG_O + e];
    for (int e = tid; e < 4096; e += 256) Ms2[(e & 63) * 65 + (e >> 6)] = Mx[e];
    __syncthreads();
    for (int e = tid; e < 4096; e += 256) {   // out[r][c] = sum_t Mx[c][t] WH[t][r]
      int r = e >> 6, c = e & 63;
      float acc = 0.f;
#pragma unroll 8
      for (int t = 0; t < 64; ++t) acc = fmaf(Ms2[t * 65 + c], Ys[t * 65 + r], acc);
      out[e] = acc;
    }
  }
}

extern "C" void kernel_launch(void* const* d_in, const int* in_sizes, int n_in,
                              void* d_out, int out_size, void* d_ws, size_t ws_size,
                              hipStream_t stream) {
  const float* fx = (const float*)d_in[0];
  const float* fy = (const float*)d_in[1];
  const float* ex = (const float*)d_in[2];
  const float* ey = (const float*)d_in[3];
  const float* Px = (const float*)d_in[4];
  const float* Py = (const float*)d_in[5];
  const float* Mx = (const float*)d_in[6];
  const float* My = (const float*)d_in[7];
  float* out = (float*)d_out;
  float* W = (float*)d_ws;

  if (ws_size < (size_t)WS_NEED * sizeof(float)) {
    hipMemsetAsync(d_out, 0, (size_t)out_size * sizeof(float), stream);
    return;
  }

  mega_kernel<<<NCG, 256, 0, stream>>>(fx, fy, ex, ey, Px, Py, Mx, My, W, out);
}

// Round 13
// 526.564 us; speedup vs baseline: 1.1474x; 1.1474x over previous
//
#include <hip/hip_runtime.h>

// V=5000, C=128, K=64. SIX launches — R8's measured-fastest split structure.
// R7/R11/R12 lesson: fused prep (wide or narrow, any barrier flavor) runs 300-440us
// while the same jobs as separate small launches execute in ~5-10us each; only the
// ~50us/launch gap remains. So: minimize dispatch count via IN-BLOCK chaining only.
// Math (R5..R12-proven): E = Ahat Ahat^T + LMB diag(r1r^2+r1i^2), Ahat = Mx^T A,
// H = My^T My; chol(E)/chol(H) congruence -> At(Y) = Y + sum_t L_t Y R_t;
// pipelined Jacobi-PCG (Ghysels-Vanroose), MAXIT=75 (absmax pinned at 2^-10 for
// MAXIT 75/100/150 — R12-validated; threshold margin 9x).
#define NV 5000
#define LMB 100.0f
#define MAXIT 75
#define TOL 1e-10f
#define NCG 16

// ---- workspace float offsets ----
#define SV_O     0
#define CTRL2_O  4352      // cg: cnt int @0; RZ floats @+64 (160); PQ @+264 (160)
#define PART_O   4864      // 80 * 8192
#define AH_O     660224
#define B0_O     668416
#define H_O      676608
#define E_O      680704
#define Z2_O     684800
#define RH_O     688896
#define TB_O     692992
#define LIH_O    697088
#define LIE_O    701184
#define BT_O     705280
#define RSTK_O   709376    // R_t, t=0..2
#define LCT_O    721664    // L_t, t=0..2 (exactly symmetric)
#define WG_O     733952
#define XG_O     738048
#define WS_NEED  742144

__device__ __forceinline__ float aload(const float* p) {
  return __hip_atomic_load(p, __ATOMIC_RELAXED, __HIP_MEMORY_SCOPE_AGENT);
}
__device__ __forceinline__ void astore(float* p, float v) {
  __hip_atomic_store(p, v, __ATOMIC_RELAXED, __HIP_MEMORY_SCOPE_AGENT);
}

// fetch-add barrier (16 blocks; R5/R8-measured ~1us incl. sync)
__device__ __forceinline__ void gbar(int* cnt, int target) {
  __syncthreads();
  if (threadIdx.x == 0) {
    __hip_atomic_fetch_add(cnt, 1, __ATOMIC_ACQ_REL, __HIP_MEMORY_SCOPE_AGENT);
    while (__hip_atomic_load(cnt, __ATOMIC_ACQUIRE, __HIP_MEMORY_SCOPE_AGENT) < target) {
      __builtin_amdgcn_s_sleep(2);
    }
  }
  __syncthreads();
}

// fused dual reduction -> one atomicAdd each from tid 0 (R8-proven)
__device__ __forceinline__ void red2a(float v1, float v2, float* red, float* d1, float* d2) {
  int tid = threadIdx.x;
  red[tid] = v1;
  red[256 + tid] = v2;
  __syncthreads();
  if (tid < 128) {
    red[tid] += red[tid + 128];
    red[256 + tid] += red[384 + tid];
  }
  __syncthreads();
  if (tid < 64) {
    float s1 = red[tid] + red[tid + 64];
    float s2 = red[256 + tid] + red[320 + tid];
#pragma unroll
    for (int o = 32; o > 0; o >>= 1) {
      s1 += __shfl_down(s1, o, 64);
      s2 += __shfl_down(s2, o, 64);
    }
    if (tid == 0) { atomicAdd(d1, s1); atomicAdd(d2, s2); }
  }
  __syncthreads();
}

// ---- plain-memory LDS staging + 64x64 GEMM helpers ----
__device__ __forceinline__ void stageN(float* dst, const float* src) {
  for (int e = threadIdx.x; e < 4096; e += 256)
    dst[(e >> 6) * 65 + (e & 63)] = src[e];
}
__device__ __forceinline__ void stageT(float* dst, const float* src) {
  for (int e = threadIdx.x; e < 4096; e += 256)
    dst[(e & 63) * 65 + (e >> 6)] = src[e];
}
__device__ __forceinline__ void mm65(const float* Ls, const float* Rs, float* D) {
  for (int e = threadIdx.x; e < 4096; e += 256) {
    int i = e >> 6, j = e & 63;
    float a0 = 0.f, a1 = 0.f;
#pragma unroll 8
    for (int t = 0; t < 64; t += 2) {
      a0 = fmaf(Ls[i * 65 + t], Rs[t * 65 + j], a0);
      a1 = fmaf(Ls[i * 65 + t + 1], Rs[(t + 1) * 65 + j], a1);
    }
    D[e] = a0 + a1;
  }
}
__device__ __forceinline__ void mm65L(const float* Ls, const float* Rs, float* Ds) {
  for (int e = threadIdx.x; e < 4096; e += 256) {
    int i = e >> 6, j = e & 63;
    float a0 = 0.f, a1 = 0.f;
#pragma unroll 8
    for (int t = 0; t < 64; t += 2) {
      a0 = fmaf(Ls[i * 65 + t], Rs[t * 65 + j], a0);
      a1 = fmaf(Ls[i * 65 + t + 1], Rs[(t + 1) * 65 + j], a1);
    }
    Ds[i * 65 + j] = a0 + a1;
  }
}

// ---- 64x64 SPD Cholesky + explicit L^-1 ----
__device__ void chol_inv(const float* S, float* Li, float* sm) {
  float (*M)[65] = (float (*)[65])sm;
  float (*T)[65] = (float (*)[65])(sm + 64 * 65);
  int tid = threadIdx.x;
  for (int e = tid; e < 4096; e += 256) {
    M[e >> 6][e & 63] = S[e];
    T[e >> 6][e & 63] = 0.f;
  }
  __syncthreads();
  for (int j = 0; j < 64; ++j) {
    float pv = M[j][j];
    __syncthreads();
    float sc = rsqrtf(pv);
    if (tid < 64 - j) M[j + tid][j] *= sc;
    __syncthreads();
    int m = 63 - j, c2 = (m * (m + 1)) >> 1;
    for (int e = tid; e < c2; e += 256) {
      int rp = (int)((sqrtf(8.f * (float)e + 1.f) - 1.f) * 0.5f);
      while (((rp + 1) * (rp + 2)) >> 1 <= e) ++rp;
      while ((rp * (rp + 1)) >> 1 > e) --rp;
      int cp = e - ((rp * (rp + 1)) >> 1);
      int r = j + 1 + rp, c = j + 1 + cp;
      M[r][c] = fmaf(-M[r][j], M[c][j], M[r][c]);
    }
    __syncthreads();
  }
  if (tid < 64) {
    int c = tid;
    T[c][c] = 1.f / M[c][c];
    for (int r = c + 1; r < 64; ++r) {
      float s = 0.f;
      for (int t = c; t < r; ++t) s = fmaf(M[r][t], T[t][c], s);
      T[r][c] = -s / M[r][r];
    }
  }
  __syncthreads();
  for (int e = tid; e < 4096; e += 256) Li[e] = T[e >> 6][e & 63];
}

// ================= K1: proj partials (80) + H (2) + sv/ctrl (1) =================
__global__ __launch_bounds__(256) void k1_kernel(const float* fx, const float* fy,
                                                 const float* ex, const float* ey,
                                                 const float* Px, const float* Py,
                                                 const float* My, float* W) {
  __shared__ float sm[8064];
  int tid = threadIdx.x, blk = blockIdx.x;
  if (blk < 80) {
    int mat = (blk >= 40), seg = mat ? (blk - 40) : blk;
    const float* P = (mat ? Py : Px);
    const float* f = (mat ? fy : fx);
    int v0 = seg * 125;
    for (int e = tid; e < 8000; e += 256) {
      int rr = e / 125, vv = e - rr * 125;
      sm[rr * 126 + vv] = P[rr * NV + v0 + vv];
    }
    __syncthreads();
    int rg = (tid >> 5) << 3;   // 8 rows
    int cq = (tid & 31) << 2;   // 4 cols
    float acc[8][4];
#pragma unroll
    for (int u = 0; u < 8; ++u)
#pragma unroll
      for (int v = 0; v < 4; ++v) acc[u][v] = 0.f;
    for (int v5 = 0; v5 < 125; v5 += 5) {
      float4 fv[5];
#pragma unroll
      for (int q = 0; q < 5; ++q)
        fv[q] = *(const float4*)(f + (size_t)(v0 + v5 + q) * 128 + cq);
#pragma unroll
      for (int q = 0; q < 5; ++q) {
#pragma unroll
        for (int u = 0; u < 8; ++u) {
          float pv = sm[(rg + u) * 126 + v5 + q];
          acc[u][0] = fmaf(pv, fv[q].x, acc[u][0]);
          acc[u][1] = fmaf(pv, fv[q].y, acc[u][1]);
          acc[u][2] = fmaf(pv, fv[q].z, acc[u][2]);
          acc[u][3] = fmaf(pv, fv[q].w, acc[u][3]);
        }
      }
    }
    float* O = W + PART_O + (size_t)blk * 8192;
#pragma unroll
    for (int u = 0; u < 8; ++u)
      *(float4*)(O + (rg + u) * 128 + cq) = make_float4(acc[u][0], acc[u][1], acc[u][2], acc[u][3]);
  } else if (blk < 82) {
    for (int e = tid; e < 4096; e += 256) sm[(e >> 6) * 65 + (e & 63)] = My[e];
    __syncthreads();
    int base = (blk - 80) * 2048;
    for (int e = tid; e < 2048; e += 256) {
      int i = (base + e) >> 6, j = (base + e) & 63;
      float a0 = 0.f, a1 = 0.f;
#pragma unroll 8
      for (int t = 0; t < 64; t += 2) {
        a0 = fmaf(sm[t * 65 + i], sm[t * 65 + j], a0);
        a1 = fmaf(sm[(t + 1) * 65 + i], sm[(t + 1) * 65 + j], a1);
      }
      W[H_O + base + e] = a0 + a1;
    }
  } else {
    if (tid < 64) {
      float vx = ex[tid], vy = ey[tid];
      float m = fmaxf(vx, vy);
#pragma unroll
      for (int o = 32; o > 0; o >>= 1) m = fmaxf(m, __shfl_xor(m, o, 64));
      float g1 = sqrtf(vx / m), g2 = sqrtf(vy / m);   // GAMMA = 0.5
      float d1 = 1.f / fmaf(g1, g1, 1.f), d2 = 1.f / fmaf(g2, g2, 1.f);
      W[SV_O + tid] = g1 * d1;          // r1r
      W[SV_O + 64 + tid] = d1;          // r1i
      W[SV_O + 128 + tid] = g2 * d2;    // d2r
      W[SV_O + 192 + tid] = d2;         // d2i
    }
    for (int e = tid; e < 512; e += 256) ((int*)(W + CTRL2_O))[e] = 0;
  }
}

// ================= K2: Ahat (0-7) + B0 (8-15) + cholH (16) =================
__global__ __launch_bounds__(256) void k2_kernel(const float* Mx, float* W) {
  __shared__ float sm[8448];
  int tid = threadIdx.x, blk = blockIdx.x;
  if (blk < 8) {
    int c0 = blk * 16;
    float* ssum = sm;          // [64][17]
    float* mxs = sm + 1088;    // [64][65]
    for (int e = tid; e < 4096; e += 256) mxs[(e >> 6) * 65 + (e & 63)] = Mx[e];
    for (int e = tid; e < 1024; e += 256) {
      int t = e >> 4, cl = e & 15;
      float s = 0.f;
#pragma unroll 8
      for (int p = 0; p < 40; ++p) s += W[PART_O + (size_t)p * 8192 + t * 128 + c0 + cl];
      ssum[t * 17 + cl] = s;
    }
    __syncthreads();
    for (int e = tid; e < 1024; e += 256) {
      int i = e >> 4, cl = e & 15;
      float a0 = 0.f, a1 = 0.f;
#pragma unroll 8
      for (int t = 0; t < 64; t += 2) {
        a0 = fmaf(mxs[t * 65 + i], ssum[t * 17 + cl], a0);
        a1 = fmaf(mxs[(t + 1) * 65 + i], ssum[(t + 1) * 17 + cl], a1);
      }
      W[AH_O + i * 128 + c0 + cl] = a0 + a1;
    }
  } else if (blk < 16) {
    int base = (blk - 8) * 1024;
    for (int e = tid; e < 1024; e += 256) {
      float s = 0.f;
#pragma unroll 8
      for (int p = 0; p < 40; ++p) s += W[PART_O + (size_t)(40 + p) * 8192 + base + e];
      W[B0_O + base + e] = s;
    }
  } else {
    chol_inv(W + H_O, W + LIH_O, sm);
  }
}

// ===== K3: E (0-3) + Z2 (4-7) + t-chains Q->U->QT->RSTK in-block (8-10) =====
__global__ __launch_bounds__(256) void k3_kernel(float* W) {
  __shared__ float sm[12800];
  int tid = threadIdx.x, blk = blockIdx.x;
  if (blk < 4) {
    for (int e = tid; e < 8192; e += 256) {
      int i = e >> 7, c = e & 127;
      sm[c * 65 + i] = W[AH_O + e];     // AhT[c][i]
    }
    __syncthreads();
    int i0 = blk * 16;
    for (int e = tid; e < 1024; e += 256) {
      int i = i0 + (e >> 6), j = e & 63;
      float a0 = 0.f, a1 = 0.f;
#pragma unroll 8
      for (int c = 0; c < 128; c += 2) {
        a0 = fmaf(sm[c * 65 + i], sm[c * 65 + j], a0);
        a1 = fmaf(sm[(c + 1) * 65 + i], sm[(c + 1) * 65 + j], a1);
      }
      float acc = a0 + a1;
      if (i == j) {
        float a = W[SV_O + i], b = W[SV_O + 64 + i];
        acc += LMB * (a * a + b * b);
      }
      W[E_O + i * 64 + j] = acc;
    }
  } else if (blk < 8) {
    int i0 = (blk - 4) * 16;
    for (int e = tid; e < 8192; e += 256) {
      int j = e >> 7, c = e & 127;
      sm[c * 65 + j] = W[B0_O + e];     // B0T[c][j]
    }
    for (int e = tid; e < 2048; e += 256) {
      int il = e >> 7, c = e & 127;
      sm[8320 + c * 17 + il] = W[AH_O + (i0 + il) * 128 + c];
    }
    __syncthreads();
    for (int e = tid; e < 1024; e += 256) {
      int il = e >> 6, j = e & 63;
      float a0 = 0.f, a1 = 0.f;
#pragma unroll 8
      for (int c = 0; c < 128; c += 2) {
        a0 = fmaf(sm[8320 + c * 17 + il], sm[c * 65 + j], a0);
        a1 = fmaf(sm[8320 + (c + 1) * 17 + il], sm[(c + 1) * 65 + j], a1);
      }
      W[Z2_O + (i0 + il) * 64 + j] = a0 + a1;
    }
  } else {
    // t-chain: Q_t -> U_t = LiH Q_t -> QT_t = U_t LiH^T -> RSTK_t = sym(QT_t)
    int t = blk - 8;
    float* smA = sm;            // LiH [64][65]
    float* smB = sm + 4160;     // Q_t / QT_t
    float* smC = sm + 8320;     // U_t
    float* sv = sm + 12480;     // 256
    for (int e = tid; e < 4096; e += 256) smA[(e >> 6) * 65 + (e & 63)] = W[LIH_O + e];
    if (tid < 256) sv[tid] = W[SV_O + tid];
    __syncthreads();
    for (int e = tid; e < 4096; e += 256) {
      int k = e >> 6, b = e & 63;
      float h = W[H_O + e], v;
      if (t == 0) v = h * (sv[128 + k] * sv[128 + b] + sv[192 + k] * sv[192 + b]);
      else if (t == 1) v = h * (sv[128 + k] + sv[128 + b]);
      else v = h * (sv[192 + k] + sv[192 + b]);
      smB[k * 65 + b] = v;
    }
    __syncthreads();
    mm65L(smA, smB, smC);                  // U = LiH * Q
    __syncthreads();
    for (int e = tid; e < 4096; e += 256) {  // QT = U * LiH^T -> smB
      int i = e >> 6, j = e & 63;
      float a0 = 0.f, a1 = 0.f;
#pragma unroll 8
      for (int b = 0; b < 64; b += 2) {
        a0 = fmaf(smC[i * 65 + b], smA[j * 65 + b], a0);
        a1 = fmaf(smC[i * 65 + b + 1], smA[j * 65 + b + 1], a1);
      }
      smB[i * 65 + j] = a0 + a1;
    }
    __syncthreads();
    for (int e = tid; e < 4096; e += 256) {
      int a = e >> 6, b = e & 63;
      W[RSTK_O + t * 4096 + e] = 0.5f * (smB[a * 65 + b] + smB[b * 65 + a]);
    }
  }
}

// ================= K4: cholE (0) + RH = Z2 H (1) =================
__global__ __launch_bounds__(256) void k4_kernel(float* W) {
  __shared__ float sm[8448];
  int blk = blockIdx.x;
  if (blk == 0) chol_inv(W + E_O, W + LIE_O, sm);
  else {
    stageN(sm, W + Z2_O); stageN(sm + 4160, W + H_O);
    __syncthreads();
    mm65(sm, sm + 4160, W + RH_O);
  }
}

// ===== K5: LCT fused from LiE (0) + TB=LiE RH -> BT=TB LiH^T chained (1) =====
__global__ __launch_bounds__(256) void k5_kernel(float* W) {
  __shared__ float sm[8448];
  int tid = threadIdx.x, blk = blockIdx.x;
  if (blk == 0) {
    for (int e = tid; e < 4096; e += 256) sm[(e >> 6) * 65 + (e & 63)] = W[LIE_O + e];
    if (tid < 128) sm[4160 + tid] = W[SV_O + tid];   // r1r @+0, r1i @+64
    __syncthreads();
    for (int e = tid; e < 4096; e += 256) {
      int i = e >> 6, j = e & 63;
      float a0 = 0.f, ar = 0.f, ai = 0.f;
#pragma unroll 4
      for (int k = 0; k < 64; ++k) {
        float l = sm[i * 65 + k] * sm[j * 65 + k];
        a0 += l;
        ar = fmaf(l, sm[4160 + k], ar);
        ai = fmaf(l, sm[4224 + k], ai);
      }
      W[LCT_O + e] = LMB * a0;
      W[LCT_O + 4096 + e] = -LMB * ar;
      W[LCT_O + 8192 + e] = -LMB * ai;
    }
  } else {
    stageN(sm, W + LIE_O); stageN(sm + 4160, W + RH_O);
    __syncthreads();
    mm65(sm, sm + 4160, W + TB_O);
    __syncthreads();
    stageN(sm, W + TB_O); stageT(sm + 4160, W + LIH_O);   // same-block L1 reuse (R12-proven)
    __syncthreads();
    mm65(sm, sm + 4160, W + BT_O);
  }
}

// ---- apply: At(Y) = Y + sum_{t=0..2} L_t (Y R_t); Y in pT[col][row] (R8 verbatim) ----
__device__ __forceinline__ float at_apply3(const float (*pT)[68], const float* Rown,
                                           float* Tt, const float* LCT,
                                           int lane, int wv, int jown) {
  if (wv >= 1) {
    const float* R0 = Rown + (wv - 1) * 256;
    float a0 = 0.f, a1 = 0.f, a2 = 0.f, a3 = 0.f;
    for (int m = 0; m < 64; ++m) {
      float pv = pT[m][lane];
      a0 = fmaf(pv, R0[m], a0);
      a1 = fmaf(pv, R0[64 + m], a1);
      a2 = fmaf(pv, R0[128 + m], a2);
      a3 = fmaf(pv, R0[192 + m], a3);
    }
    Tt[0 * 192 + (wv - 1) * 64 + lane] = a0;
    Tt[1 * 192 + (wv - 1) * 64 + lane] = a1;
    Tt[2 * 192 + (wv - 1) * 64 + lane] = a2;
    Tt[3 * 192 + (wv - 1) * 64 + lane] = a3;
  }
  __syncthreads();
  const float* Lc = LCT + lane;
  const float* Tw = Tt + wv * 192;
  float b0 = 0.f, b1 = 0.f, b2 = 0.f, b3 = 0.f;
  for (int tk = 0; tk < 192; tk += 4) {
    b0 = fmaf(Lc[(tk + 0) * 64], Tw[tk + 0], b0);
    b1 = fmaf(Lc[(tk + 1) * 64], Tw[tk + 1], b1);
    b2 = fmaf(Lc[(tk + 2) * 64], Tw[tk + 2], b2);
    b3 = fmaf(Lc[(tk + 3) * 64], Tw[tk + 3], b3);
  }
  return pT[jown][lane] + (b0 + b1) + (b2 + b3);
}

// ================= cg: R8 verbatim, MAXIT=75, + finish =================
__global__ __launch_bounds__(256) void cg_kernel(const float* Mx, float* W, float* out) {
  __shared__ float sm[8704];
  __shared__ float red[512];
  __shared__ float scal[3];
  __shared__ float sLd[192], sRd[192];
  int tid = threadIdx.x, blk = blockIdx.x;
  int lane = tid & 63, wv = tid >> 6;
  int j0 = blk * 4, jown = j0 + wv;
  float (*pT)[68] = (float (*)[68])sm;
  float* Rown = sm + 4352;
  float* Tt = sm + 5120;
  const float* BT = W + BT_O;
  const float* RSTK = W + RSTK_O;
  const float* LCT = W + LCT_O;
  float* wg = W + WG_O;
  int* cnt = (int*)(W + CTRL2_O);
  float* RZ = W + CTRL2_O + 64;
  float* PQ = W + CTRL2_O + 264;

  for (int e = tid; e < 768; e += 256) {
    int t = e >> 8, jl = (e >> 6) & 3, m = e & 63;
    Rown[t * 256 + jl * 64 + m] = RSTK[(t * 64 + j0 + jl) * 64 + m];
  }
  if (tid < 192) {
    int t = tid >> 6, i = tid & 63;
    sLd[tid] = LCT[t * 4096 + i * 64 + i];
    sRd[tid] = RSTK[t * 4096 + i * 64 + i];
  }
  __syncthreads();
  float invd = 1.f / (1.f + sLd[lane] * sRd[jown] + sLd[64 + lane] * sRd[64 + jown] +
                      sLd[128 + lane] * sRd[128 + jown]);
  for (int u = 0; u < 16; ++u) {
    int g = u * 256 + tid;               // g = col*64+row
    int col = g >> 6, row = g & 63;
    float den = 1.f + sLd[row] * sRd[col] + sLd[64 + row] * sRd[64 + col] +
                sLd[128 + row] * sRd[128 + col];
    pT[col][row] = BT[row * 64 + col] / den;
  }
  __syncthreads();
  float u_l = pT[jown][lane];
  float w_l = at_apply3(pT, Rown, Tt, LCT, lane, wv, jown);
  float r_l = BT[lane * 64 + jown];
  float m_l = invd * w_l;
  astore(&wg[jown * 64 + lane], m_l);
  red2a(r_l * u_l, w_l * u_l, red, &RZ[0], &PQ[0]);
  int bt = 0;
  gbar(cnt, (++bt) * NCG);

  float p_l = 0.f, q_l = 0.f, z_l = 0.f, s_l = 0.f, x_l = 0.f;
  float gprev = 1.f, aprev = 1.f, g0 = 1.f;
  for (int j = 0; j < MAXIT; ++j) {
    if (tid == 0) {
      scal[0] = aload(&RZ[j]);
      scal[1] = aload(&PQ[j]);
      scal[2] = aload(&RZ[0]);
    }
    __syncthreads();
    float gj = scal[0], dj = scal[1];
    if (j == 0) g0 = scal[2];
    if (j > 0 && fabsf(gj) < TOL * fabsf(g0)) break;
    float bj = (j == 0) ? 0.f : gj / gprev;
    float aj = (j == 0) ? gj / dj : gj / (dj - bj * gj / aprev);
    for (int u = 0; u < 16; ++u) {
      int g = u * 256 + tid;
      pT[g >> 6][g & 63] = aload(&wg[g]);
    }
    __syncthreads();
    float n_l = at_apply3(pT, Rown, Tt, LCT, lane, wv, jown);
    z_l = fmaf(bj, z_l, n_l);
    q_l = fmaf(bj, q_l, m_l);
    s_l = fmaf(bj, s_l, w_l);
    p_l = fmaf(bj, p_l, u_l);
    x_l = fmaf(aj, p_l, x_l);
    r_l = fmaf(-aj, s_l, r_l);
    u_l = fmaf(-aj, q_l, u_l);
    w_l = fmaf(-aj, z_l, w_l);
    m_l = invd * w_l;
    astore(&wg[jown * 64 + lane], m_l);
    red2a(r_l * u_l, w_l * u_l, red, &RZ[j + 1], &PQ[j + 1]);
    gprev = gj; aprev = aj;
    gbar(cnt, (++bt) * NCG);
  }
  astore(&W[XG_O + jown * 64 + lane], x_l);   // Y col-major
  gbar(cnt, (++bt) * NCG);

  // ---- finish (block 0): out = (Mx LiE^T Y LiH)^T ----
  if (blk == 0) {
    float* Ys = sm;           // [64][65]
    float* Ms2 = sm + 4160;   // [64][65]
    for (int e = tid; e < 4096; e += 256) Ys[(e >> 6) * 65 + (e & 63)] = aload(W + XG_O + e);
    for (int e = tid; e < 4096; e += 256) Ms2[(e >> 6) * 65 + (e & 63)] = W[LIE_O + e];
    __syncthreads();
    for (int e = tid; e < 4096; e += 256) {   // V1 = LiE^T Y  (Ys[j][i] = Y[i][j])
      int t = e >> 6, b = e & 63;
      float acc = 0.f;
#pragma unroll 8
      for (int a = 0; a < 64; ++a) acc = fmaf(Ms2[a * 65 + t], Ys[b * 65 + a], acc);
      W[WG_O + t * 64 + b] = acc;
    }
    __syncthreads();
    for (int e = tid; e < 4096; e += 256) Ys[(e >> 6) * 65 + (e & 63)] = W[WG_O + e];
    for (int e = tid; e < 4096; e += 256) Ms2[(e >> 6) * 65 + (e & 63)] = W[LIH_O + e];
    __syncthreads();
    for (int e = tid; e < 4096; e += 256) {   // WH = V1 LiH
      int t = e >> 6, c = e & 63;
      float acc = 0.f;
#pragma unroll 8
      for (int b = 0; b < 64; ++b) acc = fmaf(Ys[t * 65 + b], Ms2[b * 65 + c], acc);
      W[WG_O + t * 64 + c] = acc;
    }
    __syncthreads();
    for (int e = tid; e < 4096; e += 256) Ys[(e >> 6) * 65 + (e & 63)] = W[WG_O + e];
    for (int e = tid; e < 4096; e += 256) Ms2[(e & 63) * 65 + (e >> 6)] = Mx[e];
    __syncthreads();
    for (int e = tid; e < 4096; e += 256) {   // out[r][c] = sum_t Mx[c][t] WH[t][r]
      int r = e >> 6, c = e & 63;
      float acc = 0.f;
#pragma unroll 8
      for (int t = 0; t < 64; ++t) acc = fmaf(Ms2[t * 65 + c], Ys[t * 65 + r], acc);
      out[e] = acc;
    }
  }
}

extern "C" void kernel_launch(void* const* d_in, const int* in_sizes, int n_in,
                              void* d_out, int out_size, void* d_ws, size_t ws_size,
                              hipStream_t stream) {
  const float* fx = (const float*)d_in[0];
  const float* fy = (const float*)d_in[1];
  const float* ex = (const float*)d_in[2];
  const float* ey = (const float*)d_in[3];
  const float* Px = (const float*)d_in[4];
  const float* Py = (const float*)d_in[5];
  const float* Mx = (const float*)d_in[6];
  const float* My = (const float*)d_in[7];
  float* out = (float*)d_out;
  float* W = (float*)d_ws;

  if (ws_size < (size_t)WS_NEED * sizeof(float)) {
    hipMemsetAsync(d_out, 0, (size_t)out_size * sizeof(float), stream);
    return;
  }

  k1_kernel<<<83, 256, 0, stream>>>(fx, fy, ex, ey, Px, Py, My, W);
  k2_kernel<<<17, 256, 0, stream>>>(Mx, W);
  k3_kernel<<<11, 256, 0, stream>>>(W);
  k4_kernel<<<2, 256, 0, stream>>>(W);
  k5_kernel<<<2, 256, 0, stream>>>(W);
  cg_kernel<<<NCG, 256, 0, stream>>>(Mx, W, out);
}